// Round 1
// baseline (2537.943 us; speedup 1.0000x reference)
//
#include <hip/hip_runtime.h>

#define NN 384
#define NE 3456
#define NLb 32
#define F 64
#define KD 32

__device__ __forceinline__ float sigm(float v) { return 1.0f / (1.0f + __expf(-v)); }
__device__ __forceinline__ float tanhf_(float v) {
    float x = fminf(fmaxf(v, -15.0f), 15.0f);
    float e = __expf(2.0f * x);
    return (e - 1.0f) / (e + 1.0f);
}

__global__ void k_zero(float* p, int n) {
    int i = blockIdx.x * 256 + threadIdx.x;
    int st = gridDim.x * 256;
    for (; i < n; i += st) p[i] = 0.0f;
}

// Build count matrix C[dst*NN+src] (all edges, multiplicity, float adds of 1.0 ->
// exact & order-independent) and 0/1 Adj[src*NN+dst] (first NE-NN edges, plain store).
__global__ void k_build(const int* __restrict__ e1, const int* __restrict__ e2,
                        float* __restrict__ ws) {
    int t = blockIdx.x * 256 + threadIdx.x;
    if (t >= 2 * NE) return;
    int g = t / NE, e = t % NE;
    const int* ei = g ? e2 : e1;
    int s = ei[e], d = ei[NE + e];
    float* C   = ws + (size_t)g * NN * NN;
    float* Adj = ws + (size_t)2 * NN * NN + (size_t)g * NN * NN;
    atomicAdd(&C[d * NN + s], 1.0f);
    if (e < NE - NN) Adj[s * NN + d] = 1.0f;
}

// deg[s] = row-sum of Adj; X = [feats, deg]  (row stride 33)
__global__ void k_degx(const float* __restrict__ f1, const float* __restrict__ f2,
                       float* __restrict__ ws) {
    int g = blockIdx.y;
    int s = blockIdx.x * 64 + threadIdx.x;
    const float* feats = g ? f2 : f1;
    const float* Adj = ws + (size_t)2 * NN * NN + (size_t)g * NN * NN;
    float* X = ws + (size_t)4 * NN * NN + (size_t)g * NN * 33;
    float deg = 0.0f;
    for (int d = 0; d < NN; d++) deg += Adj[s * NN + d];
    for (int c = 0; c < NLb; c++) X[s * 33 + c] = feats[s * NLb + c];
    X[s * 33 + 32] = deg;
}

// out[g][m][n] = act( A[g][m][:] @ B[g][:,n] + bias[n] + (1+eps[li]) * resid[g][m][n] )
// block = 64 lanes (n), grid = (M, 2 graphs). A row is wave-uniform -> s_loads;
// B[k*F+n] is lane-coalesced.
__global__ __launch_bounds__(64)
void k_gemm(const float* __restrict__ A, int aGs,
            const float* __restrict__ B, int bGs,
            const float* __restrict__ bias,
            const float* __restrict__ resid, int rGs,
            const float* __restrict__ epsp, int li,
            float* __restrict__ out, int oGs, int Kdim, int act) {
    int g = blockIdx.y, m = blockIdx.x, n = threadIdx.x;
    const float* Ar = A + (size_t)g * aGs + (size_t)m * Kdim;
    const float* Bg = B + (size_t)g * bGs;
    float acc = bias ? bias[n] : 0.0f;
#pragma unroll 4
    for (int k = 0; k < Kdim; k++) acc += Ar[k] * Bg[k * F + n];
    if (resid) {
        float sc = 1.0f + (epsp ? epsp[li] : 0.0f);
        acc += sc * resid[(size_t)g * rGs + m * F + n];
    }
    if (act) acc = fmaxf(acc, 0.0f);
    out[(size_t)g * oGs + m * F + n] = acc;
}

// BatchNorm (batch stats, biased var) in-place on hs slot; also h = relu(z) -> hbuf.
__global__ __launch_bounds__(256)
void k_bn(float* __restrict__ hsb, int hsGs, float* __restrict__ hbuf, int hGs,
          const float* __restrict__ gamma, const float* __restrict__ beta) {
    __shared__ float red[4][64];
    int g = blockIdx.x;
    float* z = hsb + (size_t)g * hsGs;
    float* h = hbuf + (size_t)g * hGs;
    int c = threadIdx.x & 63, rq = threadIdx.x >> 6;
    int r0 = rq * 96;
    float s = 0.0f;
    for (int r = r0; r < r0 + 96; r++) s += z[r * F + c];
    red[rq][c] = s;
    __syncthreads();
    float mu = (red[0][c] + red[1][c] + red[2][c] + red[3][c]) * (1.0f / NN);
    __syncthreads();
    float v = 0.0f;
    for (int r = r0; r < r0 + 96; r++) { float d = z[r * F + c] - mu; v += d * d; }
    red[rq][c] = v;
    __syncthreads();
    float var = (red[0][c] + red[1][c] + red[2][c] + red[3][c]) * (1.0f / NN);
    float is = rsqrtf(var + 1e-5f);
    float ga = gamma[c], be = beta[c];
    for (int r = r0; r < r0 + 96; r++) {
        float zn = (z[r * F + c] - mu) * is * ga + be;
        z[r * F + c] = zn;
        h[r * F + c] = fmaxf(zn, 0.0f);
    }
}

// T1[l,i,e,k] = sum_d h1[l,i,d] * ged[l,k,d,e].  Block = (l,k) x i-quarter,
// M[l,k] staged in LDS (16 KB), lane = e (coalesced LDS+global loads).
__global__ __launch_bounds__(64)
void k_t1(const float* __restrict__ hs1, const float* __restrict__ ged,
          float* __restrict__ T1) {
    __shared__ float Ml[F * F];
    int l = blockIdx.x >> 5, k = blockIdx.x & 31;
    int e = threadIdx.x;
    const float* Ms = ged + ((size_t)(l * KD + k)) * F * F;
    for (int d = 0; d < F; d++) Ml[d * F + e] = Ms[d * F + e];
    __syncthreads();
    const float* h1 = hs1 + (size_t)l * NN * F;
    int i0 = blockIdx.y * 96;
    for (int i = i0; i < i0 + 96; i += 4) {
        float a0 = 0, a1 = 0, a2 = 0, a3 = 0;
#pragma unroll 8
        for (int d = 0; d < F; d++) {
            float mv = Ml[d * F + e];
            a0 += h1[(i + 0) * F + d] * mv;
            a1 += h1[(i + 1) * F + d] * mv;
            a2 += h1[(i + 2) * F + d] * mv;
            a3 += h1[(i + 3) * F + d] * mv;
        }
        T1[(((size_t)l * NN + (i + 0)) * F + e) * KD + k] = a0;
        T1[(((size_t)l * NN + (i + 1)) * F + e) * KD + k] = a1;
        T1[(((size_t)l * NN + (i + 2)) * F + e) * KD + k] = a2;
        T1[(((size_t)l * NN + (i + 3)) * F + e) * KD + k] = a3;
    }
}

// stack vector for pair (i, j=lane), layer LL:
// x[k] = sum_e T1[LL,i,e,k] * h2[LL,j,e].  T1 reads wave-uniform -> s_load.
#define COMPUTE_X(xarr, LL) do {                                               \
    _Pragma("unroll") for (int k2 = 0; k2 < KD; k2++) xarr[k2] = 0.0f;         \
    const float* t1p = T1 + (((size_t)(LL) * NN + i) * F) * KD;                \
    const float* h2p = hs2 + ((size_t)(LL) * NN + j) * F;                      \
    _Pragma("unroll 2")                                                        \
    for (int e = 0; e < F; e += 4) {                                           \
        float4 hv = *reinterpret_cast<const float4*>(h2p + e);                 \
        _Pragma("unroll") for (int k2 = 0; k2 < KD; k2++)                      \
            xarr[k2] += t1p[(e + 0) * KD + k2] * hv.x                          \
                      + t1p[(e + 1) * KD + k2] * hv.y                          \
                      + t1p[(e + 2) * KD + k2] * hv.z                          \
                      + t1p[(e + 3) * KD + k2] * hv.w;                         \
    }                                                                          \
} while (0)

// One thread per (i,j) pair; i = blockIdx.y (uniform), j = blockIdx.x*64+lane.
// Phase A: GRU over 6 layers with online-softmax attention -> pattern -> q.
// Phase B: recompute stack vector per layer, online-softmax over layers -> context.
// GRU h kept in LDS (stride-33 pad) to allow the rolled-g update without
// demoting register arrays to scratch; register mirror refreshed per step.
__global__ __launch_bounds__(64, 2)
void k_mega(const float* __restrict__ T1, const float* __restrict__ hs2,
            const float* __restrict__ wih, const float* __restrict__ whh,
            const float* __restrict__ bih, const float* __restrict__ bhh,
            const float* __restrict__ waw, const float* __restrict__ wab,
            const float* __restrict__ vat,
            const float* __restrict__ q1w, const float* __restrict__ q1b,
            const float* __restrict__ q2w, const float* __restrict__ q2b,
            const float* __restrict__ kw, const float* __restrict__ kb,
            const float* __restrict__ vw, const float* __restrict__ vb,
            float* __restrict__ out) {
    __shared__ float hl[64 * 33];
    const int i = blockIdx.y;
    const int j = blockIdx.x * 64 + threadIdx.x;
    const int TX = threadIdx.x;

    float hreg[KD], patt[KD];
#pragma unroll
    for (int k = 0; k < KD; k++) { hreg[k] = 0.0f; patt[k] = 0.0f; hl[TX * 33 + k] = 0.0f; }
    float sm = -1e30f, sden = 0.0f;

#pragma unroll 1
    for (int l = 0; l < 6; l++) {
        float x[KD];
        COMPUTE_X(x, l);
        // GRU step (merged gate loop; old h read from regs, update via LDS)
#pragma unroll 1
        for (int g = 0; g < KD; g++) {
            float ir = bih[g],          hr = bhh[g];
            float iz = bih[KD + g],     hz = bhh[KD + g];
            float in2 = bih[2 * KD + g], hn2 = bhh[2 * KD + g];
            const float* wiR = wih + g * KD;
            const float* wiZ = wih + (KD + g) * KD;
            const float* wiN = wih + (2 * KD + g) * KD;
            const float* whR = whh + g * KD;
            const float* whZ = whh + (KD + g) * KD;
            const float* whN = whh + (2 * KD + g) * KD;
#pragma unroll
            for (int k = 0; k < KD; k++) {
                float xk = x[k], hk = hreg[k];
                ir += xk * wiR[k]; iz += xk * wiZ[k]; in2 += xk * wiN[k];
                hr += hk * whR[k]; hz += hk * whZ[k]; hn2 += hk * whN[k];
            }
            float r  = sigm(ir + hr);
            float zg = sigm(iz + hz);
            float ng = tanhf_(in2 + r * hn2);
            float hold = hl[TX * 33 + g];
            hl[TX * 33 + g] = (1.0f - zg) * ng + zg * hold;
        }
#pragma unroll
        for (int k = 0; k < KD; k++) hreg[k] = hl[TX * 33 + k];
        // attention score for this layer
        float sc = 0.0f;
#pragma unroll 1
        for (int c = 0; c < KD; c++) {
            float t = wab[c];
#pragma unroll
            for (int k = 0; k < KD; k++) t += hreg[k] * waw[k * KD + c];
            sc += tanhf_(t) * vat[c];
        }
        // online softmax over layers (branchless rescale)
        float nm = fmaxf(sm, sc);
        float eo = __expf(sm - nm), en = __expf(sc - nm);
        sden = sden * eo + en;
        sm = nm;
#pragma unroll
        for (int k = 0; k < KD; k++) patt[k] = patt[k] * eo + en * hreg[k];
    }

    // pattern -> q
    float inv = 1.0f / sden;
#pragma unroll
    for (int k = 0; k < KD; k++) patt[k] *= inv;
    float t1r[KD];
#pragma unroll
    for (int c = 0; c < KD; c++) {
        float t = q1b[c];
#pragma unroll
        for (int k = 0; k < KD; k++) t += patt[k] * q1w[k * KD + c];
        t1r[c] = fmaxf(t, 0.0f);
    }
    float q[KD];
#pragma unroll
    for (int c = 0; c < KD; c++) {
        float t = q2b[c];
#pragma unroll
        for (int k = 0; k < KD; k++) t += t1r[k] * q2w[k * KD + c];
        q[c] = t;
    }
    // fold q through wk:  s_l = qdotb + x_l . qk   (saves a 32x32 matmul per layer)
    float qdotb = 0.0f;
#pragma unroll
    for (int c = 0; c < KD; c++) qdotb += q[c] * kb[c];
    float qk[KD];
#pragma unroll
    for (int k = 0; k < KD; k++) {
        float t = 0.0f;
#pragma unroll
        for (int c = 0; c < KD; c++) t += q[c] * kw[k * KD + c];
        qk[k] = t;
    }

    // Phase B: per-layer scores + value mix, online softmax over layers
    float ctx[KD];
#pragma unroll
    for (int k = 0; k < KD; k++) ctx[k] = 0.0f;
    float s2m = -1e30f, s2den = 0.0f;
#pragma unroll 1
    for (int l = 0; l < 6; l++) {
        float x[KD];
        COMPUTE_X(x, l);
        float s = qdotb;
#pragma unroll
        for (int k = 0; k < KD; k++) s += x[k] * qk[k];
        s *= 0.17677669529663687f;  // 1/sqrt(32)
        float nm = fmaxf(s2m, s);
        float eo = __expf(s2m - nm), en = __expf(s - nm);
        s2den = s2den * eo + en;
        s2m = nm;
#pragma unroll
        for (int c = 0; c < KD; c++) {
            float vc = vb[c];
#pragma unroll
            for (int k = 0; k < KD; k++) vc += x[k] * vw[k * KD + c];
            ctx[c] = ctx[c] * eo + en * vc;
        }
    }
    float invd = 1.0f / s2den;
    float* op = out + ((size_t)i * NN + j) * KD;
#pragma unroll
    for (int k = 0; k < KD; k += 4) {
        float4 w4;
        w4.x = ctx[k] * invd; w4.y = ctx[k + 1] * invd;
        w4.z = ctx[k + 2] * invd; w4.w = ctx[k + 3] * invd;
        *reinterpret_cast<float4*>(op + k) = w4;
    }
}

extern "C" void kernel_launch(void* const* d_in, const int* in_sizes, int n_in,
                              void* d_out, int out_size, void* d_ws, size_t ws_size,
                              hipStream_t stream) {
    const float* f1   = (const float*)d_in[0];
    const float* f2   = (const float*)d_in[1];
    const float* l0w1 = (const float*)d_in[2];
    const float* l0b1 = (const float*)d_in[3];
    const float* l0w2 = (const float*)d_in[4];
    const float* l0b2 = (const float*)d_in[5];
    const float* geps = (const float*)d_in[6];
    const float* gw1  = (const float*)d_in[7];
    const float* gb1  = (const float*)d_in[8];
    const float* gw2  = (const float*)d_in[9];
    const float* gb2  = (const float*)d_in[10];
    const float* gga  = (const float*)d_in[11];
    const float* gbe  = (const float*)d_in[12];
    const float* ged  = (const float*)d_in[13];
    const float* wih  = (const float*)d_in[14];
    const float* whh  = (const float*)d_in[15];
    const float* bih  = (const float*)d_in[16];
    const float* bhh  = (const float*)d_in[17];
    const float* waw  = (const float*)d_in[18];
    const float* wab  = (const float*)d_in[19];
    const float* vat  = (const float*)d_in[20];
    const float* q1w  = (const float*)d_in[21];
    const float* q1b  = (const float*)d_in[22];
    const float* q2w  = (const float*)d_in[23];
    const float* q2b  = (const float*)d_in[24];
    const float* kw   = (const float*)d_in[25];
    const float* kb   = (const float*)d_in[26];
    const float* vw   = (const float*)d_in[27];
    const float* vb   = (const float*)d_in[28];
    const int*   e1   = (const int*)d_in[29];
    const int*   e2   = (const int*)d_in[30];

    float* ws  = (float*)d_ws;
    // workspace layout (floats):
    // [0)              2*NN*NN : C (count matrix, per graph)
    // [2*NN*NN)        2*NN*NN : Adj (0/1)
    // [4*NN*NN)        2*NN*33 : X (feats+deg)
    float* X   = ws + (size_t)4 * NN * NN;
    float* H   = X + (size_t)2 * NN * 33;     // current relu(h), per graph
    float* ZB  = H + (size_t)2 * NN * F;      // z buffer
    float* TMP = ZB + (size_t)2 * NN * F;     // MLP intermediate
    float* HS  = TMP + (size_t)2 * NN * F;    // hs stack [2][6][NN][F]
    float* T1  = HS + (size_t)2 * 6 * NN * F; // [6][NN][F][KD]
    float* out = (float*)d_out;

    const int GHS = 6 * NN * F;  // per-graph hs stride
    const int GH  = NN * F;      // per-graph h stride

    k_zero<<<256, 256, 0, stream>>>(ws, 4 * NN * NN);
    k_build<<<(2 * NE + 255) / 256, 256, 0, stream>>>(e1, e2, ws);
    k_degx<<<dim3(6, 2), 64, 0, stream>>>(f1, f2, ws);
    // h0 = (relu(X@l0w1+b1))@l0w2+b2  -> HS slot 0
    k_gemm<<<dim3(NN, 2), 64, 0, stream>>>(X, NN * 33, l0w1, 0, l0b1, nullptr, 0,
                                           nullptr, 0, TMP, GH, 33, 1);
    k_gemm<<<dim3(NN, 2), 64, 0, stream>>>(TMP, GH, l0w2, 0, l0b2, nullptr, 0,
                                           nullptr, 0, HS, GHS, F, 0);
    for (int li = 0; li < 5; li++) {
        const float* hp = (li == 0) ? HS : H;
        int hGs = (li == 0) ? GHS : GH;
        // z = C@h + (1+eps)h
        k_gemm<<<dim3(NN, 2), 64, 0, stream>>>(ws, NN * NN, hp, hGs, nullptr,
                                               hp, hGs, geps, li, ZB, GH, NN, 0);
        // MLP
        k_gemm<<<dim3(NN, 2), 64, 0, stream>>>(ZB, GH, gw1 + li * F * F, 0,
                                               gb1 + li * F, nullptr, 0, nullptr, 0,
                                               TMP, GH, F, 1);
        k_gemm<<<dim3(NN, 2), 64, 0, stream>>>(TMP, GH, gw2 + li * F * F, 0,
                                               gb2 + li * F, nullptr, 0, nullptr, 0,
                                               HS + (li + 1) * GH, GHS, F, 0);
        // BN + h = relu(z)
        k_bn<<<2, 256, 0, stream>>>(HS + (li + 1) * GH, GHS, H, GH,
                                    gga + li * F, gbe + li * F);
    }
    k_t1<<<dim3(192, 4), 64, 0, stream>>>(HS, ged, T1);
    k_mega<<<dim3(6, NN), 64, 0, stream>>>(T1, HS + GHS, wih, whh, bih, bhh,
                                           waw, wab, vat, q1w, q1b, q2w, q2b,
                                           kw, kb, vw, vb, out);
}

// Round 3
// 1782.589 us; speedup vs baseline: 1.4237x; 1.4237x over previous
//
#include <hip/hip_runtime.h>
#include <stdint.h>

#define NN 384
#define NE 3456
#define NLb 32
#define F 64
#define KD 32

typedef short shortx8 __attribute__((ext_vector_type(8)));
typedef float floatx4 __attribute__((ext_vector_type(4)));

__device__ __forceinline__ float sigm(float v) { return 1.0f / (1.0f + __expf(-v)); }
__device__ __forceinline__ float tanhf_(float v) {
    float x = fminf(fmaxf(v, -15.0f), 15.0f);
    float e = __expf(2.0f * x);
    return (e - 1.0f) / (e + 1.0f);
}
__device__ __forceinline__ uint16_t f2bf(float f) {
    uint32_t u = __float_as_uint(f);
    uint32_t r = (u + 0x7fffu + ((u >> 16) & 1u)) >> 16;
    return (uint16_t)r;
}
__device__ __forceinline__ float bf2f(uint16_t h) {
    return __uint_as_float((uint32_t)h << 16);
}

__global__ void k_zero(float* p, int n) {
    int i = blockIdx.x * 256 + threadIdx.x;
    int st = gridDim.x * 256;
    for (; i < n; i += st) p[i] = 0.0f;
}

__global__ void k_build(const int* __restrict__ e1, const int* __restrict__ e2,
                        float* __restrict__ C, float* __restrict__ Adj) {
    int t = blockIdx.x * 256 + threadIdx.x;
    if (t >= 2 * NE) return;
    int g = t / NE, e = t % NE;
    const int* ei = g ? e2 : e1;
    int s = ei[e], d = ei[NE + e];
    atomicAdd(&C[(size_t)g * NN * NN + d * NN + s], 1.0f);
    if (e < NE - NN) Adj[(size_t)g * NN * NN + s * NN + d] = 1.0f;
}

__global__ void k_degx(const float* __restrict__ f1, const float* __restrict__ f2,
                       const float* __restrict__ Adj, float* __restrict__ X) {
    int g = blockIdx.y;
    int s = blockIdx.x * 64 + threadIdx.x;
    const float* feats = g ? f2 : f1;
    const float* A = Adj + (size_t)g * NN * NN;
    float* Xg = X + (size_t)g * NN * 33;
    float deg = 0.0f;
    for (int d = 0; d < NN; d++) deg += A[s * NN + d];
    for (int c = 0; c < NLb; c++) Xg[s * 33 + c] = feats[s * NLb + c];
    Xg[s * 33 + 32] = deg;
}

// h0 row: relu(Xrow@w1+b1)@w2+b2  (single wave, LDS broadcast between the two mats)
__global__ __launch_bounds__(64)
void k_lin0(const float* __restrict__ X, const float* __restrict__ w1,
            const float* __restrict__ b1, const float* __restrict__ w2,
            const float* __restrict__ b2, float* __restrict__ HS) {
    __shared__ float tl[64];
    int g = blockIdx.y, m = blockIdx.x, n = threadIdx.x;
    const float* Xr = X + (size_t)g * NN * 33 + m * 33;
    float t = b1[n];
#pragma unroll
    for (int k = 0; k < 33; k++) t += Xr[k] * w1[k * F + n];
    t = fmaxf(t, 0.0f);
    tl[n] = t;
    __syncthreads();
    float o = b2[n];
#pragma unroll 4
    for (int k = 0; k < F; k++) o += tl[k] * w2[k * F + n];
    HS[(size_t)g * (6 * NN * F) + m * F + n] = o;
}

// One GIN layer row: z = C@h + (1+eps)h ; out = relu(z@W1+b1)@W2+b2
__global__ __launch_bounds__(64)
void k_gin(const float* __restrict__ C, const float* __restrict__ hin, int hGs,
           const float* __restrict__ gw1, const float* __restrict__ gb1,
           const float* __restrict__ gw2, const float* __restrict__ gb2,
           const float* __restrict__ geps, int li,
           float* __restrict__ zout, int oGs) {
    __shared__ float zl[64], tl[64];
    int g = blockIdx.y, m = blockIdx.x, n = threadIdx.x;
    const float* Crow = C + (size_t)g * NN * NN + (size_t)m * NN;
    const float* h = hin + (size_t)g * hGs;
    float acc = 0.0f;
#pragma unroll 4
    for (int k = 0; k < NN; k++) acc += Crow[k] * h[k * F + n];
    acc += (1.0f + geps[li]) * h[m * F + n];
    zl[n] = acc;
    __syncthreads();
    const float* W1 = gw1 + (size_t)li * F * F;
    const float* W2 = gw2 + (size_t)li * F * F;
    float t = gb1[li * F + n];
#pragma unroll 4
    for (int k = 0; k < F; k++) t += zl[k] * W1[k * F + n];
    t = fmaxf(t, 0.0f);
    tl[n] = t;
    __syncthreads();
    float o = gb2[li * F + n];
#pragma unroll 4
    for (int k = 0; k < F; k++) o += tl[k] * W2[k * F + n];
    zout[(size_t)g * oGs + m * F + n] = o;
}

__global__ __launch_bounds__(256)
void k_bn(float* __restrict__ hsb, int hsGs, float* __restrict__ hbuf, int hGs,
          const float* __restrict__ gamma, const float* __restrict__ beta) {
    __shared__ float red[4][64];
    int g = blockIdx.x;
    float* z = hsb + (size_t)g * hsGs;
    float* h = hbuf + (size_t)g * hGs;
    int c = threadIdx.x & 63, rq = threadIdx.x >> 6;
    int r0 = rq * 96;
    float s = 0.0f;
    for (int r = r0; r < r0 + 96; r++) s += z[r * F + c];
    red[rq][c] = s;
    __syncthreads();
    float mu = (red[0][c] + red[1][c] + red[2][c] + red[3][c]) * (1.0f / NN);
    __syncthreads();
    float v = 0.0f;
    for (int r = r0; r < r0 + 96; r++) { float d = z[r * F + c] - mu; v += d * d; }
    red[rq][c] = v;
    __syncthreads();
    float var = (red[0][c] + red[1][c] + red[2][c] + red[3][c]) * (1.0f / NN);
    float is = rsqrtf(var + 1e-5f);
    float ga = gamma[c], be = beta[c];
    for (int r = r0; r < r0 + 96; r++) {
        float zn = (z[r * F + c] - mu) * is * ga + be;
        z[r * F + c] = zn;
        h[r * F + c] = fmaxf(zn, 0.0f);
    }
}

// f32 HS -> bf16 hi/lo split arrays (hi = rne(v), lo = rne(v - hi))
__global__ void k_cvt2(const float* __restrict__ HS, uint16_t* __restrict__ hhi,
                       uint16_t* __restrict__ hlo) {
    int idx = blockIdx.x * 256 + threadIdx.x;
    if (idx >= 2 * 6 * NN * F) return;
    float v = HS[idx];
    uint16_t h = f2bf(v);
    hhi[idx] = h;
    hlo[idx] = f2bf(v - bf2f(h));
}

// ged[l,k,d,e] f32 -> gedT[l, k*64+e, d] hi/lo bf16
__global__ __launch_bounds__(64)
void k_gedT2(const float* __restrict__ ged, uint16_t* __restrict__ ghi,
             uint16_t* __restrict__ glo) {
    __shared__ float t[64 * 65];
    int lk = blockIdx.x, lane = threadIdx.x;
    const float* src = ged + (size_t)lk * 4096;
    for (int d = 0; d < 64; d++) t[lane * 65 + d] = src[d * 64 + lane];  // t[e][d]
    __syncthreads();
    for (int e = 0; e < 64; e++) {
        float v = t[e * 65 + lane];
        uint16_t h = f2bf(v);
        ghi[(size_t)lk * 4096 + e * 64 + lane] = h;
        glo[(size_t)lk * 4096 + e * 64 + lane] = f2bf(v - bf2f(h));
    }
}

// T1[l,i,n=k*64+e] = sum_d gedT[l,n,d]*h1[l,i,d]  (hi/lo 3-product MFMA, f32 acc,
// stored as hi/lo bf16). Block 256 = 2x2 waves of 64x64 tiles; grid (16,3,6).
__global__ __launch_bounds__(256)
void k_t1m2(const uint16_t* __restrict__ gThi, const uint16_t* __restrict__ gTlo,
            const uint16_t* __restrict__ hbhi, const uint16_t* __restrict__ hblo,
            uint16_t* __restrict__ T1hi, uint16_t* __restrict__ T1lo) {
    int l = blockIdx.z;
    int w = threadIdx.x >> 6, lane = threadIdx.x & 63;
    int nb = blockIdx.x * 128 + (w >> 1) * 64;
    int ib = blockIdx.y * 128 + (w & 1) * 64;
    int lr = lane & 15, lq = lane >> 4;
    const uint16_t* gah = gThi + (size_t)l * 2048 * 64;
    const uint16_t* gal = gTlo + (size_t)l * 2048 * 64;
    const uint16_t* gbh = hbhi + (size_t)l * NN * F;  // graph 1
    const uint16_t* gbl = hblo + (size_t)l * NN * F;
    shortx8 Ah[4][2], Al[4][2];
#pragma unroll
    for (int s = 0; s < 4; s++)
#pragma unroll
        for (int ks = 0; ks < 2; ks++) {
            size_t off = (size_t)(nb + s * 16 + lr) * 64 + ks * 32 + lq * 8;
            Ah[s][ks] = *reinterpret_cast<const shortx8*>(gah + off);
            Al[s][ks] = *reinterpret_cast<const shortx8*>(gal + off);
        }
#pragma unroll
    for (int si = 0; si < 4; si++) {
        shortx8 Bh[2], Bl[2];
#pragma unroll
        for (int ks = 0; ks < 2; ks++) {
            size_t off = (size_t)(ib + si * 16 + lr) * 64 + ks * 32 + lq * 8;
            Bh[ks] = *reinterpret_cast<const shortx8*>(gbh + off);
            Bl[ks] = *reinterpret_cast<const shortx8*>(gbl + off);
        }
#pragma unroll
        for (int sn = 0; sn < 4; sn++) {
            floatx4 a = (floatx4){0.f, 0.f, 0.f, 0.f};
#pragma unroll
            for (int ks = 0; ks < 2; ks++) {
                a = __builtin_amdgcn_mfma_f32_16x16x32_bf16(Ah[sn][ks], Bh[ks], a, 0, 0, 0);
                a = __builtin_amdgcn_mfma_f32_16x16x32_bf16(Ah[sn][ks], Bl[ks], a, 0, 0, 0);
                a = __builtin_amdgcn_mfma_f32_16x16x32_bf16(Al[sn][ks], Bh[ks], a, 0, 0, 0);
            }
            size_t addr = ((size_t)l * NN + (ib + si * 16 + lr)) * 2048 + (nb + sn * 16 + lq * 4);
            uint2 hv, lv;
            uint16_t h0 = f2bf(a[0]), h1 = f2bf(a[1]), h2 = f2bf(a[2]), h3 = f2bf(a[3]);
            hv.x = (uint32_t)h0 | ((uint32_t)h1 << 16);
            hv.y = (uint32_t)h2 | ((uint32_t)h3 << 16);
            uint16_t l0 = f2bf(a[0] - bf2f(h0)), l1 = f2bf(a[1] - bf2f(h1));
            uint16_t l2 = f2bf(a[2] - bf2f(h2)), l3 = f2bf(a[3] - bf2f(h3));
            lv.x = (uint32_t)l0 | ((uint32_t)l1 << 16);
            lv.y = (uint32_t)l2 | ((uint32_t)l3 << 16);
            *reinterpret_cast<uint2*>(T1hi + addr) = hv;
            *reinterpret_cast<uint2*>(T1lo + addr) = lv;
        }
    }
}

// Per wave, layer LL: x-tile [64 j][32 k] = T1(l,i) x h2 via hi/lo MFMA -> LDS xb
#define MFMA_X(LL) do {                                                        \
    const uint16_t* tAh = T1hi_ + ((size_t)(LL) * NN + i) * 2048;              \
    const uint16_t* tAl = T1lo_ + ((size_t)(LL) * NN + i) * 2048;              \
    shortx8 Ah[2][2], Al[2][2];                                                \
    _Pragma("unroll") for (int kt = 0; kt < 2; kt++)                           \
    _Pragma("unroll") for (int eh = 0; eh < 2; eh++) {                         \
        int off = (kt * 16 + lr) * 64 + eh * 32 + lq * 8;                      \
        Ah[kt][eh] = *reinterpret_cast<const shortx8*>(tAh + off);             \
        Al[kt][eh] = *reinterpret_cast<const shortx8*>(tAl + off);             \
    }                                                                          \
    const uint16_t* tBh = hbhi + ((size_t)(6 + (LL)) * NN + j0w) * 64;         \
    const uint16_t* tBl = hblo + ((size_t)(6 + (LL)) * NN + j0w) * 64;         \
    _Pragma("unroll") for (int jt = 0; jt < 4; jt++) {                         \
        shortx8 Bh[2], Bl[2];                                                  \
        _Pragma("unroll") for (int eh = 0; eh < 2; eh++) {                     \
            int boff = (jt * 16 + lr) * 64 + eh * 32 + lq * 8;                 \
            Bh[eh] = *reinterpret_cast<const shortx8*>(tBh + boff);            \
            Bl[eh] = *reinterpret_cast<const shortx8*>(tBl + boff);            \
        }                                                                      \
        _Pragma("unroll") for (int kt = 0; kt < 2; kt++) {                     \
            floatx4 a = (floatx4){0.f, 0.f, 0.f, 0.f};                         \
            _Pragma("unroll") for (int eh = 0; eh < 2; eh++) {                 \
                a = __builtin_amdgcn_mfma_f32_16x16x32_bf16(Ah[kt][eh], Bh[eh], a, 0, 0, 0); \
                a = __builtin_amdgcn_mfma_f32_16x16x32_bf16(Ah[kt][eh], Bl[eh], a, 0, 0, 0); \
                a = __builtin_amdgcn_mfma_f32_16x16x32_bf16(Al[kt][eh], Bh[eh], a, 0, 0, 0); \
            }                                                                  \
            float* xw = xb + (w * 64 + jt * 16 + lr) * 33 + kt * 16 + lq * 4;  \
            xw[0] = a[0]; xw[1] = a[1]; xw[2] = a[2]; xw[3] = a[3];            \
        }                                                                      \
    }                                                                          \
} while (0)

// Block = 192 threads (3 waves) = 192 j's for one i. Per layer: MFMA x into
// wave-private LDS, then per-thread f32 GRU/attention (round-1-verified logic).
__global__ __launch_bounds__(192, 2)
void k_mega3(const uint16_t* __restrict__ T1hi_, const uint16_t* __restrict__ T1lo_,
             const uint16_t* __restrict__ hbhi, const uint16_t* __restrict__ hblo,
             const float* __restrict__ wih, const float* __restrict__ whh,
             const float* __restrict__ bih, const float* __restrict__ bhh,
             const float* __restrict__ waw, const float* __restrict__ wab,
             const float* __restrict__ vat,
             const float* __restrict__ q1w, const float* __restrict__ q1b,
             const float* __restrict__ q2w, const float* __restrict__ q2b,
             const float* __restrict__ kw, const float* __restrict__ kb,
             const float* __restrict__ vw, const float* __restrict__ vb,
             float* __restrict__ out) {
    __shared__ float xb[192 * 33];
    __shared__ float hl[192 * 33];
    const int i = blockIdx.y, jseg = blockIdx.x;
    const int TX = threadIdx.x;
    const int w = TX >> 6, lane = TX & 63, lr = lane & 15, lq = lane >> 4;
    const int j0w = jseg * 192 + w * 64;
    const int jself = jseg * 192 + TX;

    float hreg[KD], patt[KD];
#pragma unroll
    for (int k = 0; k < KD; k++) { hreg[k] = 0.0f; patt[k] = 0.0f; hl[TX * 33 + k] = 0.0f; }
    float sm = -1e30f, sden = 0.0f;

#pragma unroll 1
    for (int l = 0; l < 6; l++) {
        MFMA_X(l);
        float x[KD];
#pragma unroll
        for (int k = 0; k < KD; k++) x[k] = xb[TX * 33 + k];
#pragma unroll 2
        for (int g = 0; g < KD; g++) {
            float ir = bih[g],           hr = bhh[g];
            float iz = bih[KD + g],      hz = bhh[KD + g];
            float in2 = bih[2 * KD + g], hn2 = bhh[2 * KD + g];
            const float* wiR = wih + g * KD;
            const float* wiZ = wih + (KD + g) * KD;
            const float* wiN = wih + (2 * KD + g) * KD;
            const float* whR = whh + g * KD;
            const float* whZ = whh + (KD + g) * KD;
            const float* whN = whh + (2 * KD + g) * KD;
#pragma unroll
            for (int k = 0; k < KD; k++) {
                float xk = x[k], hk = hreg[k];
                ir += xk * wiR[k]; iz += xk * wiZ[k]; in2 += xk * wiN[k];
                hr += hk * whR[k]; hz += hk * whZ[k]; hn2 += hk * whN[k];
            }
            float r  = sigm(ir + hr);
            float zg = sigm(iz + hz);
            float ng = tanhf_(in2 + r * hn2);
            float hold = hl[TX * 33 + g];
            hl[TX * 33 + g] = (1.0f - zg) * ng + zg * hold;
        }
#pragma unroll
        for (int k = 0; k < KD; k++) hreg[k] = hl[TX * 33 + k];
        float sc = 0.0f;
#pragma unroll 1
        for (int c = 0; c < KD; c++) {
            float t = wab[c];
#pragma unroll
            for (int k = 0; k < KD; k++) t += hreg[k] * waw[k * KD + c];
            sc += tanhf_(t) * vat[c];
        }
        float nm = fmaxf(sm, sc);
        float eo = __expf(sm - nm), en = __expf(sc - nm);
        sden = sden * eo + en;
        sm = nm;
#pragma unroll
        for (int k = 0; k < KD; k++) patt[k] = patt[k] * eo + en * hreg[k];
    }

    float inv = 1.0f / sden;
#pragma unroll
    for (int k = 0; k < KD; k++) patt[k] *= inv;
    float t1r[KD];
#pragma unroll
    for (int c = 0; c < KD; c++) {
        float t = q1b[c];
#pragma unroll
        for (int k = 0; k < KD; k++) t += patt[k] * q1w[k * KD + c];
        t1r[c] = fmaxf(t, 0.0f);
    }
    float q[KD];
#pragma unroll
    for (int c = 0; c < KD; c++) {
        float t = q2b[c];
#pragma unroll
        for (int k = 0; k < KD; k++) t += t1r[k] * q2w[k * KD + c];
        q[c] = t;
    }
    float qdotb = 0.0f;
#pragma unroll
    for (int c = 0; c < KD; c++) qdotb += q[c] * kb[c];
    float qk[KD];
#pragma unroll
    for (int k = 0; k < KD; k++) {
        float t = 0.0f;
#pragma unroll
        for (int c = 0; c < KD; c++) t += q[c] * kw[k * KD + c];
        qk[k] = t;
    }

    float ctx[KD];
#pragma unroll
    for (int k = 0; k < KD; k++) ctx[k] = 0.0f;
    float s2m = -1e30f, s2den = 0.0f;
#pragma unroll 1
    for (int l = 0; l < 6; l++) {
        MFMA_X(l);
        float x[KD];
#pragma unroll
        for (int k = 0; k < KD; k++) x[k] = xb[TX * 33 + k];
        float s = qdotb;
#pragma unroll
        for (int k = 0; k < KD; k++) s += x[k] * qk[k];
        s *= 0.17677669529663687f;
        float nm = fmaxf(s2m, s);
        float eo = __expf(s2m - nm), en = __expf(s - nm);
        s2den = s2den * eo + en;
        s2m = nm;
#pragma unroll 2
        for (int c = 0; c < KD; c++) {
            float vc = vb[c];
#pragma unroll
            for (int k = 0; k < KD; k++) vc += x[k] * vw[k * KD + c];
            ctx[c] = ctx[c] * eo + en * vc;
        }
    }
    float invd = 1.0f / s2den;
    float* op = out + ((size_t)i * NN + jself) * KD;
#pragma unroll
    for (int k = 0; k < KD; k += 4) {
        float4 w4;
        w4.x = ctx[k] * invd; w4.y = ctx[k + 1] * invd;
        w4.z = ctx[k + 2] * invd; w4.w = ctx[k + 3] * invd;
        *reinterpret_cast<float4*>(op + k) = w4;
    }
}

extern "C" void kernel_launch(void* const* d_in, const int* in_sizes, int n_in,
                              void* d_out, int out_size, void* d_ws, size_t ws_size,
                              hipStream_t stream) {
    const float* f1   = (const float*)d_in[0];
    const float* f2   = (const float*)d_in[1];
    const float* l0w1 = (const float*)d_in[2];
    const float* l0b1 = (const float*)d_in[3];
    const float* l0w2 = (const float*)d_in[4];
    const float* l0b2 = (const float*)d_in[5];
    const float* geps = (const float*)d_in[6];
    const float* gw1  = (const float*)d_in[7];
    const float* gb1  = (const float*)d_in[8];
    const float* gw2  = (const float*)d_in[9];
    const float* gb2  = (const float*)d_in[10];
    const float* gga  = (const float*)d_in[11];
    const float* gbe  = (const float*)d_in[12];
    const float* ged  = (const float*)d_in[13];
    const float* wih  = (const float*)d_in[14];
    const float* whh  = (const float*)d_in[15];
    const float* bih  = (const float*)d_in[16];
    const float* bhh  = (const float*)d_in[17];
    const float* waw  = (const float*)d_in[18];
    const float* wab  = (const float*)d_in[19];
    const float* vat  = (const float*)d_in[20];
    const float* q1w  = (const float*)d_in[21];
    const float* q1b  = (const float*)d_in[22];
    const float* q2w  = (const float*)d_in[23];
    const float* q2b  = (const float*)d_in[24];
    const float* kw   = (const float*)d_in[25];
    const float* kb   = (const float*)d_in[26];
    const float* vw   = (const float*)d_in[27];
    const float* vb   = (const float*)d_in[28];
    const int*   e1   = (const int*)d_in[29];
    const int*   e2   = (const int*)d_in[30];

    // ---- workspace layout ----
    float* C   = (float*)d_ws;                                 // 2*NN*NN
    float* Adj = C + (size_t)2 * NN * NN;                      // 2*NN*NN
    float* X   = Adj + (size_t)2 * NN * NN;                    // 2*NN*33
    float* H   = X + (size_t)2 * NN * 33;                      // 2*NN*F
    float* HS  = H + (size_t)2 * NN * F;                       // [2][6][NN][F]
    uint16_t* hbhi = (uint16_t*)(HS + (size_t)2 * 6 * NN * F); // [2][6][NN][F]
    uint16_t* hblo = hbhi + (size_t)2 * 6 * NN * F;
    uint16_t* gThi = hblo + (size_t)2 * 6 * NN * F;            // [6][2048][64]
    uint16_t* gTlo = gThi + (size_t)6 * 2048 * 64;
    uint16_t* T1hi = gTlo + (size_t)6 * 2048 * 64;             // [6][NN][2048]
    uint16_t* T1lo = T1hi + (size_t)6 * NN * 2048;
    float* out = (float*)d_out;

    const int GHS = 6 * NN * F;
    const int GH  = NN * F;

    k_zero<<<576, 256, 0, stream>>>(C, 4 * NN * NN);
    k_build<<<(2 * NE + 255) / 256, 256, 0, stream>>>(e1, e2, C, Adj);
    k_degx<<<dim3(6, 2), 64, 0, stream>>>(f1, f2, Adj, X);
    k_lin0<<<dim3(NN, 2), 64, 0, stream>>>(X, l0w1, l0b1, l0w2, l0b2, HS);
    for (int li = 0; li < 5; li++) {
        const float* hp = (li == 0) ? HS : H;
        int hGs = (li == 0) ? GHS : GH;
        k_gin<<<dim3(NN, 2), 64, 0, stream>>>(C, hp, hGs, gw1, gb1, gw2, gb2,
                                              geps, li, HS + (li + 1) * GH, GHS);
        k_bn<<<2, 256, 0, stream>>>(HS + (li + 1) * GH, GHS, H, GH,
                                    gga + li * F, gbe + li * F);
    }
    k_cvt2<<<(2 * 6 * NN * F + 255) / 256, 256, 0, stream>>>(HS, hbhi, hblo);
    k_gedT2<<<6 * KD, 64, 0, stream>>>(ged, gThi, gTlo);
    k_t1m2<<<dim3(16, 3, 6), 256, 0, stream>>>(gThi, gTlo, hbhi, hblo, T1hi, T1lo);
    k_mega3<<<dim3(2, NN), 192, 0, stream>>>(T1hi, T1lo, hbhi, hblo,
                                             wih, whh, bih, bhh, waw, wab, vat,
                                             q1w, q1b, q2w, q2b, kw, kb, vw, vb, out);
}